// Round 2
// baseline (103.186 us; speedup 1.0000x reference)
//
#include <hip/hip_runtime.h>
#include <hip/hip_bf16.h>
#include <cfloat>

#define BLOCK 256
#define RPT 4   // rows per thread

// Set min arrays to UINT_MAX (any nonneg float bit pattern is smaller).
__global__ void init_kernel(unsigned int* __restrict__ p, int count) {
    int i = blockIdx.x * blockDim.x + threadIdx.x;
    if (i < count) p[i] = 0xFFFFFFFFu;
}

// blockIdx.z==0: rows=A (true), cols=B (pred)  -> min_a  ("mins")
// blockIdx.z==1: rows=B (pred), cols=A (true)  -> min_b  ("mins_seeds")
// Each thread owns RPT rows, block processes a slice of columns staged in LDS.
__global__ __launch_bounds__(BLOCK) void pairmin_kernel(
    const float* __restrict__ A, const float* __restrict__ B,
    unsigned int* __restrict__ min_a, unsigned int* __restrict__ min_b,
    int n, int m, int colsPerSlice)
{
    const float* X; const float* Y;
    unsigned int* outmin; int nx, ny;
    if (blockIdx.z == 0) { X = A; Y = B; outmin = min_a; nx = n; ny = m; }
    else                 { X = B; Y = A; outmin = min_b; nx = m; ny = n; }

    const int tid = threadIdx.x;
    const int rowBase = blockIdx.x * (BLOCK * RPT);
    if (rowBase >= nx) return;                       // block-uniform exit

    const int colBeg = blockIdx.y * colsPerSlice;
    if (colBeg >= ny) return;                        // block-uniform exit
    const int colEnd = min(colBeg + colsPerSlice, ny);

    float rx[RPT], ry[RPT], rz[RPT], mn[RPT];
    bool valid[RPT];
#pragma unroll
    for (int k = 0; k < RPT; ++k) {
        int r = rowBase + tid + k * BLOCK;
        valid[k] = (r < nx);
        int rr = valid[k] ? r : 0;
        rx[k] = X[3 * rr + 0];
        ry[k] = X[3 * rr + 1];
        rz[k] = X[3 * rr + 2];
        mn[k] = FLT_MAX;
    }

    __shared__ float4 cols[BLOCK];
    for (int c0 = colBeg; c0 < colEnd; c0 += BLOCK) {
        const int cnt = min(BLOCK, colEnd - c0);
        if (tid < cnt) {
            const int c = c0 + tid;
            cols[tid] = make_float4(Y[3 * c + 0], Y[3 * c + 1], Y[3 * c + 2], 0.f);
        }
        __syncthreads();
#pragma unroll 2
        for (int j = 0; j < cnt; ++j) {
            const float4 cc = cols[j];   // broadcast ds_read_b128, conflict-free
#pragma unroll
            for (int k = 0; k < RPT; ++k) {
                float dx = rx[k] - cc.x;
                float dy = ry[k] - cc.y;
                float dz = rz[k] - cc.z;
                float d2 = fmaf(dz, dz, fmaf(dy, dy, dx * dx));
                mn[k] = fminf(mn[k], d2);
            }
        }
        __syncthreads();
    }

#pragma unroll
    for (int k = 0; k < RPT; ++k) {
        if (valid[k])
            atomicMin(&outmin[rowBase + tid + k * BLOCK], __float_as_uint(mn[k]));
    }
}

// Single block: sqrt the min-d2 arrays, write mins_seeds, reduce both means,
// write the three scalars. out layout: [loss+loss_seeds, mins_seeds(m), loss, loss_seeds]
__global__ __launch_bounds__(1024) void finalize_kernel(
    const unsigned int* __restrict__ min_a, const unsigned int* __restrict__ min_b,
    float* __restrict__ out, int n, int m)
{
    float sa = 0.f, sb = 0.f;
    for (int i = threadIdx.x; i < n; i += 1024)
        sa += sqrtf(__uint_as_float(min_a[i]));
    for (int i = threadIdx.x; i < m; i += 1024) {
        float v = sqrtf(__uint_as_float(min_b[i]));
        out[1 + i] = v;                       // mins_seeds
        sb += v;
    }
#pragma unroll
    for (int off = 32; off > 0; off >>= 1) {
        sa += __shfl_down(sa, off, 64);
        sb += __shfl_down(sb, off, 64);
    }
    __shared__ float reda[16], redb[16];
    const int wave = threadIdx.x >> 6;
    const int lane = threadIdx.x & 63;
    if (lane == 0) { reda[wave] = sa; redb[wave] = sb; }
    __syncthreads();
    if (threadIdx.x == 0) {
        float ta = 0.f, tb = 0.f;
        for (int w = 0; w < 16; ++w) { ta += reda[w]; tb += redb[w]; }
        const float loss = ta / (float)n;
        const float loss_seeds = tb / (float)m;
        out[0] = loss + loss_seeds;
        out[1 + m] = loss;
        out[2 + m] = loss_seeds;
    }
}

extern "C" void kernel_launch(void* const* d_in, const int* in_sizes, int n_in,
                              void* d_out, int out_size, void* d_ws, size_t ws_size,
                              hipStream_t stream) {
    const int n = in_sizes[0] / 3;   // true_pos count
    const int m = in_sizes[1] / 3;   // pred_pos count
    const float* A = (const float*)d_in[0];
    const float* B = (const float*)d_in[1];
    float* out = (float*)d_out;
    unsigned int* min_a = (unsigned int*)d_ws;
    unsigned int* min_b = min_a + n;

    const int total = n + m;
    init_kernel<<<(total + 255) / 256, 256, 0, stream>>>(min_a, total);

    const int maxnm = (n > m) ? n : m;
    const int gx = (maxnm + BLOCK * RPT - 1) / (BLOCK * RPT);
    const int slices = 64;
    const int colsPerSlice = (maxnm + slices - 1) / slices;
    dim3 grid(gx, slices, 2);
    pairmin_kernel<<<grid, BLOCK, 0, stream>>>(A, B, min_a, min_b, n, m, colsPerSlice);

    finalize_kernel<<<1, 1024, 0, stream>>>(min_a, min_b, out, n, m);
}

// Round 4
// 90.842 us; speedup vs baseline: 1.1359x; 1.1359x over previous
//
#include <hip/hip_runtime.h>
#include <hip/hip_bf16.h>
#include <cfloat>

#define BLOCK 256
#define RPT 8      // rows per thread -> 2048 rows per block
#define SLICES 64  // column slices per side

// Order-preserving float <-> uint maps (total order matches float order).
static __device__ __forceinline__ unsigned f2key(float f) {
    unsigned b = __float_as_uint(f);
    return (b & 0x80000000u) ? ~b : (b ^ 0x80000000u);
}
static __device__ __forceinline__ float key2f(unsigned k) {
    unsigned b = (k & 0x80000000u) ? (k ^ 0x80000000u) : ~k;
    return __uint_as_float(b);
}

// blockIdx.z==0: rows=A (true), cols=B (pred)  -> min_a  ("mins")
// blockIdx.z==1: rows=B (pred), cols=A (true)  -> min_b  ("mins_seeds")
// Minimize s = ||y||^2/2 - x.y  (3 FMA + 1 fmin per pair); d2 = ||x||^2 + 2s
// reconstructed in finalize. In-register fminf is float-correct; the global
// combine uses the order-preserving uint key (s is usually NEGATIVE, so raw
// int bit-pattern atomicMin is WRONG — learned in round 3).
__global__ __launch_bounds__(BLOCK) void pairmin_kernel(
    const float* __restrict__ A, const float* __restrict__ B,
    unsigned* __restrict__ min_a, unsigned* __restrict__ min_b,
    int n, int m, int colsPerSlice)
{
    const float* X; const float* Y;
    unsigned* outmin; int nx_, ny_;
    if (blockIdx.z == 0) { X = A; Y = B; outmin = min_a; nx_ = n; ny_ = m; }
    else                 { X = B; Y = A; outmin = min_b; nx_ = m; ny_ = n; }

    const int tid = threadIdx.x;
    const int rowBase = blockIdx.x * (BLOCK * RPT);
    if (rowBase >= nx_) return;                      // block-uniform exit

    const int colBeg = blockIdx.y * colsPerSlice;
    if (colBeg >= ny_) return;                       // block-uniform exit
    const int colEnd = min(colBeg + colsPerSlice, ny_);

    float nrx[RPT], nry[RPT], nrz[RPT], mn[RPT];
    bool valid[RPT];
#pragma unroll
    for (int k = 0; k < RPT; ++k) {
        int r = rowBase + tid + k * BLOCK;
        valid[k] = (r < nx_);
        int rr = valid[k] ? r : 0;
        nrx[k] = -X[3 * rr + 0];
        nry[k] = -X[3 * rr + 1];
        nrz[k] = -X[3 * rr + 2];
        mn[k] = FLT_MAX;
    }

    __shared__ float4 cols[BLOCK];
    for (int c0 = colBeg; c0 < colEnd; c0 += BLOCK) {
        const int cnt = min(BLOCK, colEnd - c0);
        if (tid < cnt) {
            const int c = c0 + tid;
            const float yx = Y[3 * c + 0];
            const float yy = Y[3 * c + 1];
            const float yz = Y[3 * c + 2];
            const float halfny = 0.5f * fmaf(yx, yx, fmaf(yy, yy, yz * yz));
            cols[tid] = make_float4(yx, yy, yz, halfny);
        }
        __syncthreads();
#pragma unroll 4
        for (int j = 0; j < cnt; ++j) {
            const float4 cc = cols[j];   // wave-uniform broadcast, conflict-free
#pragma unroll
            for (int k = 0; k < RPT; ++k) {
                float s = fmaf(nrx[k], cc.x,
                          fmaf(nry[k], cc.y,
                          fmaf(nrz[k], cc.z, cc.w)));
                mn[k] = fminf(mn[k], s);
            }
        }
        __syncthreads();
    }

#pragma unroll
    for (int k = 0; k < RPT; ++k) {
        if (valid[k])
            atomicMin(&outmin[rowBase + tid + k * BLOCK], f2key(mn[k]));
    }
}

#define FBLOCKS 128
// ws header: hdr[0]=sumA(f32), hdr[1]=sumB(f32), hdr[2]=ticket(u32)
// out layout: [loss+loss_seeds, mins_seeds(m), loss, loss_seeds]
__global__ __launch_bounds__(256) void finalize_kernel(
    const float* __restrict__ A, const float* __restrict__ B,
    const unsigned* __restrict__ min_a, const unsigned* __restrict__ min_b,
    float* __restrict__ hdr, float* __restrict__ out, int n, int m)
{
    const int stride = gridDim.x * 256;
    const int start = blockIdx.x * 256 + threadIdx.x;

    float sa = 0.f, sb = 0.f;
    for (int i = start; i < n; i += stride) {
        const float ax = A[3 * i + 0], ay = A[3 * i + 1], az = A[3 * i + 2];
        const float nrm = fmaf(ax, ax, fmaf(ay, ay, az * az));
        const float s  = key2f(min_a[i]);
        const float d2 = fmaxf(fmaf(2.f, s, nrm), 0.f);
        sa += sqrtf(d2);
    }
    for (int i = start; i < m; i += stride) {
        const float bx = B[3 * i + 0], by = B[3 * i + 1], bz = B[3 * i + 2];
        const float nrm = fmaf(bx, bx, fmaf(by, by, bz * bz));
        const float s  = key2f(min_b[i]);
        const float d2 = fmaxf(fmaf(2.f, s, nrm), 0.f);
        const float v = sqrtf(d2);
        out[1 + i] = v;                  // mins_seeds
        sb += v;
    }

#pragma unroll
    for (int off = 32; off > 0; off >>= 1) {
        sa += __shfl_down(sa, off, 64);
        sb += __shfl_down(sb, off, 64);
    }
    __shared__ float reda[4], redb[4];
    const int wave = threadIdx.x >> 6;
    const int lane = threadIdx.x & 63;
    if (lane == 0) { reda[wave] = sa; redb[wave] = sb; }
    __syncthreads();

    if (threadIdx.x == 0) {
        float ta = reda[0] + reda[1] + reda[2] + reda[3];
        float tb = redb[0] + redb[1] + redb[2] + redb[3];
        atomicAdd(&hdr[0], ta);
        atomicAdd(&hdr[1], tb);
        __threadfence();
        unsigned ticket = atomicAdd((unsigned*)&hdr[2], 1u);
        if (ticket == (unsigned)(gridDim.x - 1)) {
            const float fa = atomicAdd(&hdr[0], 0.f);   // coherent read of totals
            const float fb = atomicAdd(&hdr[1], 0.f);
            const float loss = fa / (float)n;
            const float loss_seeds = fb / (float)m;
            out[0] = loss + loss_seeds;
            out[1 + m] = loss;
            out[2 + m] = loss_seeds;
        }
    }
}

extern "C" void kernel_launch(void* const* d_in, const int* in_sizes, int n_in,
                              void* d_out, int out_size, void* d_ws, size_t ws_size,
                              hipStream_t stream) {
    const int n = in_sizes[0] / 3;   // true_pos count
    const int m = in_sizes[1] / 3;   // pred_pos count
    const float* A = (const float*)d_in[0];
    const float* B = (const float*)d_in[1];
    float* out = (float*)d_out;

    float* hdr = (float*)d_ws;                 // 32-byte header
    unsigned* min_a = (unsigned*)((char*)d_ws + 32);
    unsigned* min_b = min_a + n;

    // hdr <- 0; min-key arrays <- 0xFFFFFFFF (max key, i.e. +inf in key space)
    hipMemsetAsync(d_ws, 0, 32, stream);
    hipMemsetAsync((void*)min_a, 0xFF, (size_t)(n + m) * 4, stream);

    const int maxnm = (n > m) ? n : m;
    const int gx = (maxnm + BLOCK * RPT - 1) / (BLOCK * RPT);
    const int colsPerSlice = (maxnm + SLICES - 1) / SLICES;
    dim3 grid(gx, SLICES, 2);
    pairmin_kernel<<<grid, BLOCK, 0, stream>>>(A, B, min_a, min_b, n, m, colsPerSlice);

    finalize_kernel<<<FBLOCKS, 256, 0, stream>>>(A, B, min_a, min_b, hdr, out, n, m);
}